// Round 10
// baseline (215.720 us; speedup 1.0000x reference)
//
#include <hip/hip_runtime.h>
#include <hip/hip_bf16.h>
#include <stdint.h>

// Problem constants
#define HID 1024
#define SEQ 2048
#define BATCH 2
#define NHEADS 16
#define HEADDIM 64
#define MROWS (BATCH*SEQ)   // 4096

#define GAS __attribute__((address_space(1)))
#define LAS __attribute__((address_space(3)))

typedef __attribute__((ext_vector_type(8))) __bf16 bf16x8;
typedef __attribute__((ext_vector_type(4))) float f32x4;
typedef __attribute__((ext_vector_type(16))) float f32x16;

__device__ __forceinline__ ushort f2bf(float f) {
  union { float f; uint32_t u; } v; v.f = f;
  return (ushort)((v.u + 0x7FFFu + ((v.u >> 16) & 1u)) >> 16);
}

__device__ __forceinline__ void gl_lds16(const void* g, void* l) {
  __builtin_amdgcn_global_load_lds((const GAS void*)g, (LAS void*)l, 16, 0, 0);
}

// pack 2 f32 -> 2 bf16 in one u32 (lo = a, hi = b), RNE
__device__ __forceinline__ uint32_t cvtpk(float a, float b) {
  uint32_t r;
  asm("v_cvt_pk_bf16_f32 %0, %1, %2" : "=v"(r) : "v"(a), "v"(b));
  return r;
}

// swap: a_hi <-> b_lo  =>  a' = [a_lo, b_lo], b' = [a_hi, b_hi]
__device__ __forceinline__ void pl32swap(uint32_t& a, uint32_t& b) {
  asm("v_permlane32_swap_b32 %0, %1" : "+v"(a), "+v"(b));
}

// ---------------- weight fp32 -> bf16 convert ----------------
__global__ __launch_bounds__(256) void k_cvt(const float* __restrict__ Wq,
                                             const float* __restrict__ Wk,
                                             const float* __restrict__ Wv,
                                             const float* __restrict__ Wo,
                                             ushort* __restrict__ dst) {
  int mat = blockIdx.y;
  const float* src = (mat == 0) ? Wq : (mat == 1) ? Wk : (mat == 2) ? Wv : Wo;
  int off = (blockIdx.x * 256 + threadIdx.x) * 4;
  float4 v = *(const float4*)(src + off);
  ushort4 o;
  o.x = f2bf(v.x); o.y = f2bf(v.y); o.z = f2bf(v.z); o.w = f2bf(v.w);
  *(ushort4*)(dst + (size_t)mat * (HID * HID) + off) = o;
}

// ---------------- LayerNorm fp32 -> bf16 ----------------
__global__ __launch_bounds__(256) void k_ln(const float* __restrict__ x,
                                            const float* __restrict__ g,
                                            const float* __restrict__ b,
                                            ushort* __restrict__ xn) {
  int row = blockIdx.x;
  int t = threadIdx.x;
  const float* xr = x + (size_t)row * HID;
  float4 v = *(const float4*)(xr + t * 4);
  float s = v.x + v.y + v.z + v.w;
  float s2 = v.x * v.x + v.y * v.y + v.z * v.z + v.w * v.w;
  for (int m = 1; m < 64; m <<= 1) { s += __shfl_xor(s, m); s2 += __shfl_xor(s2, m); }
  __shared__ float ws[4], ws2[4];
  int wid = t >> 6;
  if ((t & 63) == 0) { ws[wid] = s; ws2[wid] = s2; }
  __syncthreads();
  s = ws[0] + ws[1] + ws[2] + ws[3];
  s2 = ws2[0] + ws2[1] + ws2[2] + ws2[3];
  float mu = s * (1.0f / HID);
  float var = s2 * (1.0f / HID) - mu * mu;
  float rstd = rsqrtf(var + 1e-5f);
  float4 gg = *(const float4*)(g + t * 4);
  float4 bb = *(const float4*)(b + t * 4);
  ushort4 o;
  o.x = f2bf((v.x - mu) * rstd * gg.x + bb.x);
  o.y = f2bf((v.y - mu) * rstd * gg.y + bb.y);
  o.z = f2bf((v.z - mu) * rstd * gg.z + bb.z);
  o.w = f2bf((v.w - mu) * rstd * gg.w + bb.w);
  *(ushort4*)(xn + (size_t)row * HID + t * 4) = o;
}

// ---------------- fused QKV GEMM (v3: 32x32x16 MFMA) ----------------
// Same 128x128 tile / BK=32 / simple 2-barrier loop (pipelined variant regressed
// via occupancy loss, round 7). CHANGE: 16x16x32 -> 32x32x16 MFMA: per K-step
// per wave 8 MFMA (was 16) + 4 ds_read_b128 (was 8); LDS pattern stays
// minimum-bank-occupancy. C layout (verified in attn): col=lane&31,
// row=(r&3)+8*(r>>2)+4*(lane>>5). Epilogue stores 64B/wave contiguous (l32
// spans 32 cols); V-transposed path packs 4 consecutive sidx into ushort4.
__global__ __launch_bounds__(256) void k_qkv(const ushort* __restrict__ xn,
                                             const ushort* __restrict__ wmat,
                                             const float* __restrict__ bq,
                                             const float* __restrict__ bk,
                                             const float* __restrict__ bv,
                                             ushort* __restrict__ qo,
                                             ushort* __restrict__ ko,
                                             ushort* __restrict__ vo) {
  __shared__ ushort As[128 * 32];
  __shared__ ushort Bs[128 * 32];
  int tid = threadIdx.x;
  int lane = tid & 63;
  int wv = tid >> 6;
  int l32 = lane & 31, hi = lane >> 5;
  int m0 = blockIdx.x * 128;
  int ng = blockIdx.y * 128;
  int mat = ng >> 10;            // 0,1,2
  int nloc = ng & 1023;
  const ushort* wptr = wmat + (size_t)mat * (HID * HID) + (size_t)nloc * HID;
  const float* bias = (mat == 0) ? bq : (mat == 1) ? bk : bv;
  ushort* outp = (mat == 0) ? qo : (mat == 1) ? ko : vo;
  const float scl = (mat == 0) ? 0.18033688011112042f : 1.0f;

  int arow = tid >> 2;
  int acol = (tid & 3) * 8;
  int wm = (wv >> 1) * 64, wn = (wv & 1) * 64;

  f32x16 acc[2][2] = {};
  for (int k0 = 0; k0 < HID; k0 += 32) {
    __syncthreads();
    for (int t = 0; t < 2; t++) {
      gl_lds16(xn + (size_t)(m0 + t * 64 + arow) * HID + k0 + acol,
               As + t * 2048 + wv * 512);
      gl_lds16(wptr + (size_t)(t * 64 + arow) * HID + k0 + acol,
               Bs + t * 2048 + wv * 512);
    }
    __syncthreads();
#pragma unroll
    for (int kh = 0; kh < 2; kh++) {
      bf16x8 af[2], bfr[2];
#pragma unroll
      for (int mt = 0; mt < 2; mt++)
        af[mt] = *(const bf16x8*)&As[(wm + mt * 32 + l32) * 32 + kh * 16 + hi * 8];
#pragma unroll
      for (int nt = 0; nt < 2; nt++)
        bfr[nt] = *(const bf16x8*)&Bs[(wn + nt * 32 + l32) * 32 + kh * 16 + hi * 8];
#pragma unroll
      for (int mt = 0; mt < 2; mt++)
#pragma unroll
        for (int nt = 0; nt < 2; nt++)
          acc[mt][nt] = __builtin_amdgcn_mfma_f32_32x32x16_bf16(af[mt], bfr[nt], acc[mt][nt], 0, 0, 0);
    }
  }

  // epilogue. C: col = wn + nt*32 + l32, row = wm + mt*32 + (r&3)+8*(r>>2)+4*hi.
  float bv2[2];
#pragma unroll
  for (int nt = 0; nt < 2; nt++) bv2[nt] = bias[nloc + wn + nt * 32 + l32];
#pragma unroll
  for (int mt = 0; mt < 2; mt++) {
#pragma unroll
    for (int nt = 0; nt < 2; nt++) {
      int col = nloc + wn + nt * 32 + l32;
      int h = col >> 6, d = col & 63;
      if (mat == 2) {
        // V transposed [bh][d][s]: consecutive r (within group g) -> consecutive sidx.
#pragma unroll
        for (int g = 0; g < 4; g++) {
          int m = m0 + wm + mt * 32 + 8 * g + 4 * hi;   // + (r&3) below
          int bidx = m >> 11, sidx = m & 2047;
          ushort4 o;
          o.x = f2bf((acc[mt][nt][g * 4 + 0] + bv2[nt]) * scl);
          o.y = f2bf((acc[mt][nt][g * 4 + 1] + bv2[nt]) * scl);
          o.z = f2bf((acc[mt][nt][g * 4 + 2] + bv2[nt]) * scl);
          o.w = f2bf((acc[mt][nt][g * 4 + 3] + bv2[nt]) * scl);
          size_t dst = (((size_t)(bidx * NHEADS + h) * HEADDIM) + d) * SEQ + sidx;
          *(ushort4*)(outp + dst) = o;
        }
      } else {
#pragma unroll
        for (int r = 0; r < 16; r++) {
          int m = m0 + wm + mt * 32 + (r & 3) + 8 * (r >> 2) + 4 * hi;
          int bidx = m >> 11, sidx = m & 2047;
          size_t dst = (((size_t)(bidx * NHEADS + h) * SEQ) + sidx) * HEADDIM + d;
          outp[dst] = f2bf((acc[mt][nt][r] + bv2[nt]) * scl);
        }
      }
    }
  }
}

// ---------------- flash attention v6 (proven 52.0us, reverted from stagger) --------
// v8 stagger REGRESSED (52->62): barrier phase-locks co-resident blocks; PV-first
// order also exposed the QK->softmax dependency across the barrier. v6 order
// (QK -> SM+PV of t-1) gives that dependency a full body of slack. Keep v6.
#define E2(x) __builtin_amdgcn_exp2f(x)

#define SOFTMAX_PF(S0, S1)                                                     \
    union { uint32_t u[4]; bf16x8 v; } pf0, pf1, pf2, pf3;                     \
    {                                                                          \
      uint32_t c0 = cvtpk(E2(S0[0]),  E2(S0[1]));                              \
      uint32_t c1 = cvtpk(E2(S0[2]),  E2(S0[3]));                              \
      uint32_t c2 = cvtpk(E2(S0[4]),  E2(S0[5]));                              \
      uint32_t c3 = cvtpk(E2(S0[6]),  E2(S0[7]));                              \
      uint32_t c4 = cvtpk(E2(S0[8]),  E2(S0[9]));                              \
      uint32_t c5 = cvtpk(E2(S0[10]), E2(S0[11]));                             \
      uint32_t c6 = cvtpk(E2(S0[12]), E2(S0[13]));                             \
      uint32_t c7 = cvtpk(E2(S0[14]), E2(S0[15]));                             \
      pl32swap(c0, c2); pl32swap(c1, c3); pl32swap(c4, c6); pl32swap(c5, c7);  \
      pf0.u[0] = c0; pf0.u[1] = c1; pf0.u[2] = c2; pf0.u[3] = c3;              \
      pf1.u[0] = c4; pf1.u[1] = c5; pf1.u[2] = c6; pf1.u[3] = c7;              \
    }                                                                          \
    {                                                                          \
      uint32_t c0 = cvtpk(E2(S1[0]),  E2(S1[1]));                              \
      uint32_t c1 = cvtpk(E2(S1[2]),  E2(S1[3]));                              \
      uint32_t c2 = cvtpk(E2(S1[4]),  E2(S1[5]));                              \
      uint32_t c3 = cvtpk(E2(S1[6]),  E2(S1[7]));                              \
      uint32_t c4 = cvtpk(E2(S1[8]),  E2(S1[9]));                              \
      uint32_t c5 = cvtpk(E2(S1[10]), E2(S1[11]));                             \
      uint32_t c6 = cvtpk(E2(S1[12]), E2(S1[13]));                             \
      uint32_t c7 = cvtpk(E2(S1[14]), E2(S1[15]));                             \
      pl32swap(c0, c2); pl32swap(c1, c3); pl32swap(c4, c6); pl32swap(c5, c7);  \
      pf2.u[0] = c0; pf2.u[1] = c1; pf2.u[2] = c2; pf2.u[3] = c3;              \
      pf3.u[0] = c4; pf3.u[1] = c5; pf3.u[2] = c6; pf3.u[3] = c7;              \
    }

#define ATTN_BODY(T, SC0, SC1, SP0, SP1, DO_DMA, WAITN)                        \
  do {                                                                         \
    if (DO_DMA) {                                                              \
      size_t ko = (size_t)((T) + 2) * 64 * HEADDIM;                            \
      size_t vo = (size_t)((T) + 2) * 64;                                      \
      gl_lds16(kSrcA + ko, &Ksm[kd][ldsA]);                                    \
      gl_lds16(kSrcB + ko, &Ksm[kd][ldsB]);                                    \
      gl_lds16(vSrcA + vo, &Vsm[vd][ldsA]);                                    \
      gl_lds16(vSrcB + vo, &Vsm[vd][ldsB]);                                    \
    }                                                                          \
    SC0 = (f32x16){}; SC1 = (f32x16){};                                        \
    __builtin_amdgcn_s_setprio(1);                                             \
    _Pragma("unroll")                                                          \
    for (int f = 0; f < 4; f++) {                                              \
      int g = 2 * f + hi;                                                      \
      bf16x8 k0 = *(const bf16x8*)&Ksm[kr][l32 * 64 + ((g ^ rsw) * 8)];        \
      bf16x8 k1 = *(const bf16x8*)&Ksm[kr][(32 + l32) * 64 + ((g ^ rsw) * 8)]; \
      SC0 = __builtin_amdgcn_mfma_f32_32x32x16_bf16(k0, qf[f], SC0, 0, 0, 0);  \
      SC1 = __builtin_amdgcn_mfma_f32_32x32x16_bf16(k1, qf[f], SC1, 0, 0, 0);  \
    }                                                                          \
    __builtin_amdgcn_s_setprio(0);                                             \
    bf16x8 vf[8];                                                              \
    _Pragma("unroll")                                                          \
    for (int kf = 0; kf < 4; kf++) {                                           \
      int g = 2 * kf + hi;                                                     \
      vf[2 * kf]     = *(const bf16x8*)&Vsm[vr][l32 * 64 + ((g ^ rsw) * 8)];   \
      vf[2 * kf + 1] = *(const bf16x8*)&Vsm[vr][(32 + l32) * 64 + ((g ^ rsw) * 8)]; \
    }                                                                          \
    SOFTMAX_PF(SP0, SP1)                                                       \
    __builtin_amdgcn_s_setprio(1);                                             \
    _Pragma("unroll")                                                          \
    for (int kf = 0; kf < 4; kf++) {                                           \
      bf16x8 pv = (kf == 0) ? pf0.v : (kf == 1) ? pf1.v : (kf == 2) ? pf2.v : pf3.v; \
      Oa0 = __builtin_amdgcn_mfma_f32_32x32x16_bf16(pv, vf[2 * kf], Oa0, 0, 0, 0);   \
      Oa1 = __builtin_amdgcn_mfma_f32_32x32x16_bf16(pv, vf[2 * kf + 1], Oa1, 0, 0, 0); \
      Os  = __builtin_amdgcn_mfma_f32_32x32x16_bf16(pv, ones, Os, 0, 0, 0);    \
    }                                                                          \
    __builtin_amdgcn_s_setprio(0);                                             \
    asm volatile("s_waitcnt vmcnt(" #WAITN ")" ::: "memory");                  \
    __builtin_amdgcn_s_barrier();                                              \
    __builtin_amdgcn_sched_barrier(0);                                         \
    kr = (kr == 2) ? 0 : kr + 1;                                               \
    kd = (kd == 2) ? 0 : kd + 1;                                               \
    vr = (vr + 1) & 3;                                                         \
    vd = (vd + 1) & 3;                                                         \
  } while (0)

__global__ __launch_bounds__(256, 2) void k_attn(const ushort* __restrict__ Q,
                                                 const ushort* __restrict__ K,
                                                 const ushort* __restrict__ Vt,
                                                 ushort* __restrict__ ctx) {
  __shared__ ushort Ksm[3][64 * 64];   // 24 KB
  __shared__ ushort Vsm[4][64 * 64];   // 32 KB
  int tid = threadIdx.x, lane = tid & 63, wv = tid >> 6;
  int l32 = lane & 31, hi = lane >> 5;
  int bh = blockIdx.x;                 // XCD-grouped: id%8 == bh%8 (v5)
  int q0 = blockIdx.y * 128;
  const ushort* Qb = Q + ((size_t)bh * SEQ + q0 + wv * 32 + l32) * HEADDIM;
  const ushort* Kb = K + (size_t)bh * SEQ * HEADDIM;
  const ushort* Vb = Vt + (size_t)bh * HEADDIM * SEQ;   // [d][s]

  // Q as B-frag: col=l32 (q-row), k(d) = f*16 + hi*8 + j. Pre-scaled by 0.125*log2e.
  bf16x8 qf[4];
#pragma unroll
  for (int f = 0; f < 4; f++)
    qf[f] = *(const bf16x8*)(Qb + f * 16 + hi * 8);

  bf16x8 ones;
#pragma unroll
  for (int j = 0; j < 8; j++) ones[j] = (__bf16)1.0f;

  int gsl = lane & 7;
  int rowA = wv * 8 + (lane >> 3);        // rows 0..31
  int rowB = 32 + wv * 8 + (lane >> 3);   // rows 32..63
  const ushort* kSrcA = Kb + rowA * HEADDIM + ((gsl ^ (rowA & 7)) * 8);
  const ushort* kSrcB = Kb + rowB * HEADDIM + ((gsl ^ (rowB & 7)) * 8);
  const ushort* vSrcA = Vb + (size_t)rowA * SEQ + ((gsl ^ (rowA & 7)) * 8);
  const ushort* vSrcB = Vb + (size_t)rowB * SEQ + ((gsl ^ (rowB & 7)) * 8);
  int ldsA = wv * 512;          // ushort idx (1 KB per wave-issue)
  int ldsB = 2048 + wv * 512;

  f32x16 Oa0 = {}, Oa1 = {}, Os = {};
  f32x16 sA0, sA1, sB0, sB1;
  int rsw = (l32 & 7);   // read-side swizzle key

  // prologue: stage tile 0 -> K[0]/V[0], tile 1 -> K[1]/V[1].
  gl_lds16(kSrcA, &Ksm[0][ldsA]);
  gl_lds16(kSrcB, &Ksm[0][ldsB]);
  gl_lds16(vSrcA, &Vsm[0][ldsA]);
  gl_lds16(vSrcB, &Vsm[0][ldsB]);
  gl_lds16(kSrcA + 64 * HEADDIM, &Ksm[1][ldsA]);
  gl_lds16(kSrcB + 64 * HEADDIM, &Ksm[1][ldsB]);
  gl_lds16(vSrcA + 64, &Vsm[1][ldsA]);
  gl_lds16(vSrcB + 64, &Vsm[1][ldsB]);
  asm volatile("s_waitcnt vmcnt(4)" ::: "memory");   // tile0 landed
  __builtin_amdgcn_s_barrier();
  __builtin_amdgcn_sched_barrier(0);

  // t = 0 (peeled): DMA tile 2 -> K[2]/V[2], QK(0) -> sA. No softmax/PV yet.
  {
    gl_lds16(kSrcA + 2 * 64 * HEADDIM, &Ksm[2][ldsA]);
    gl_lds16(kSrcB + 2 * 64 * HEADDIM, &Ksm[2][ldsB]);
    gl_lds16(vSrcA + 2 * 64, &Vsm[2][ldsA]);
    gl_lds16(vSrcB + 2 * 64, &Vsm[2][ldsB]);
    sA0 = (f32x16){}; sA1 = (f32x16){};
    __builtin_amdgcn_s_setprio(1);
#pragma unroll
    for (int f = 0; f < 4; f++) {
      int g = 2 * f + hi;
      bf16x8 k0 = *(const bf16x8*)&Ksm[0][l32 * 64 + ((g ^ rsw) * 8)];
      bf16x8 k1 = *(const bf16x8*)&Ksm[0][(32 + l32) * 64 + ((g ^ rsw) * 8)];
      sA0 = __builtin_amdgcn_mfma_f32_32x32x16_bf16(k0, qf[f], sA0, 0, 0, 0);
      sA1 = __builtin_amdgcn_mfma_f32_32x32x16_bf16(k1, qf[f], sA1, 0, 0, 0);
    }
    __builtin_amdgcn_s_setprio(0);
    asm volatile("s_waitcnt vmcnt(4)" ::: "memory");   // tile1 landed; tile2 in flight
    __builtin_amdgcn_s_barrier();
    __builtin_amdgcn_sched_barrier(0);
  }

  // steady state. At entry of body t: kr=t%3, kd=(t+2)%3, vr=(t-1)%4, vd=(t+2)%4.
  int kr = 1, kd = 0, vr = 0, vd = 3;
  for (int t = 1; t < 29; t += 2) {
    ATTN_BODY(t,     sB0, sB1, sA0, sA1, true, 4);
    ATTN_BODY(t + 1, sA0, sA1, sB0, sB1, true, 4);
  }
  ATTN_BODY(29, sB0, sB1, sA0, sA1, true, 4);
  ATTN_BODY(30, sA0, sA1, sB0, sB1, false, 0);   // last landing: tile31 must arrive

  // t = 31 tail: QK(31) -> sB from K[31%3=1], softmax+PV(30) from V[30%4=2].
  {
    sB0 = (f32x16){}; sB1 = (f32x16){};
    __builtin_amdgcn_s_setprio(1);
#pragma unroll
    for (int f = 0; f < 4; f++) {
      int g = 2 * f + hi;
      bf16x8 k0 = *(const bf16x8*)&Ksm[kr][l32 * 64 + ((g ^ rsw) * 8)];
      bf16x8 k1 = *(const bf16x8*)&Ksm[kr][(32 + l32) * 64 + ((g ^ rsw) * 8)];
      sB0 = __builtin_amdgcn_mfma_f32_32x32x16_bf16(k0, qf[f], sB0, 0, 0, 0);
      sB1 = __builtin_amdgcn_mfma_f32_32x32x16_bf16(k1, qf[f], sB1, 0, 0, 0);
    }
    __builtin_amdgcn_s_setprio(0);
    bf16x8 vf[8];
#pragma unroll
    for (int kf = 0; kf < 4; kf++) {
      int g = 2 * kf + hi;
      vf[2 * kf]     = *(const bf16x8*)&Vsm[vr][l32 * 64 + ((g ^ rsw) * 8)];
      vf[2 * kf + 1] = *(const bf16x8*)&Vsm[vr][(32 + l32) * 64 + ((g ^ rsw) * 8)];
    }
    SOFTMAX_PF(sA0, sA1)
    __builtin_amdgcn_s_setprio(1);
#pragma unroll
    for (int kf = 0; kf < 4; kf++) {
      bf16x8 pv = (kf == 0) ? pf0.v : (kf == 1) ? pf1.v : (kf == 2) ? pf2.v : pf3.v;
      Oa0 = __builtin_amdgcn_mfma_f32_32x32x16_bf16(pv, vf[2 * kf], Oa0, 0, 0, 0);
      Oa1 = __builtin_amdgcn_mfma_f32_32x32x16_bf16(pv, vf[2 * kf + 1], Oa1, 0, 0, 0);
      Os  = __builtin_amdgcn_mfma_f32_32x32x16_bf16(pv, ones, Os, 0, 0, 0);
    }
    __builtin_amdgcn_s_setprio(0);
    vr = (vr + 1) & 3;   // -> 31%4 = 3 for the epilogue PV(31)
  }

  // epilogue: softmax+PV of tile 31 (scores in sB, V(31) in Vsm[3])
  {
    bf16x8 vf[8];
#pragma unroll
    for (int kf = 0; kf < 4; kf++) {
      int g = 2 * kf + hi;
      vf[2 * kf]     = *(const bf16x8*)&Vsm[vr][l32 * 64 + ((g ^ rsw) * 8)];
      vf[2 * kf + 1] = *(const bf16x8*)&Vsm[vr][(32 + l32) * 64 + ((g ^ rsw) * 8)];
    }
    SOFTMAX_PF(sB0, sB1)
    __builtin_amdgcn_s_setprio(1);
#pragma unroll
    for (int kf = 0; kf < 4; kf++) {
      bf16x8 pv = (kf == 0) ? pf0.v : (kf == 1) ? pf1.v : (kf == 2) ? pf2.v : pf3.v;
      Oa0 = __builtin_amdgcn_mfma_f32_32x32x16_bf16(pv, vf[2 * kf], Oa0, 0, 0, 0);
      Oa1 = __builtin_amdgcn_mfma_f32_32x32x16_bf16(pv, vf[2 * kf + 1], Oa1, 0, 0, 0);
      Os  = __builtin_amdgcn_mfma_f32_32x32x16_bf16(pv, ones, Os, 0, 0, 0);
    }
    __builtin_amdgcn_s_setprio(0);
  }

  // epilogue: ctx[b*2048+s][h*64+d] bf16. q in regs: (r&3)+8*(r>>2)+4*hi.
  int bidx = bh >> 4, h = bh & 15;
#pragma unroll
  for (int r = 0; r < 16; r++) {
    float inv = 1.0f / Os[r];
    int qloc = (r & 3) + 8 * (r >> 2) + 4 * hi;
    int sidx = q0 + wv * 32 + qloc;
    size_t base = ((size_t)(bidx * SEQ) + sidx) * HID + h * HEADDIM;
    ctx[base + l32]      = f2bf(Oa0[r] * inv);
    ctx[base + 32 + l32] = f2bf(Oa1[r] * inv);
  }
}

// ---------------- output projection (v3: 32x32x16 MFMA) + bias + residual ----------
__global__ __launch_bounds__(256) void k_oproj(const ushort* __restrict__ ctx,
                                               const ushort* __restrict__ wmat,
                                               const float* __restrict__ bo,
                                               const float* __restrict__ x,
                                               float* __restrict__ out) {
  __shared__ ushort As[128 * 32];
  __shared__ ushort Bs[128 * 32];
  int tid = threadIdx.x;
  int lane = tid & 63;
  int wv = tid >> 6;
  int l32 = lane & 31, hi = lane >> 5;
  int m0 = blockIdx.x * 128;
  int n0 = blockIdx.y * 128;
  const ushort* wptr = wmat + (size_t)3 * (HID * HID) + (size_t)n0 * HID;  // Wo
  int arow = tid >> 2;
  int acol = (tid & 3) * 8;
  int wm = (wv >> 1) * 64, wn = (wv & 1) * 64;

  f32x16 acc[2][2] = {};
  for (int k0 = 0; k0 < HID; k0 += 32) {
    __syncthreads();
    for (int t = 0; t < 2; t++) {
      gl_lds16(ctx + (size_t)(m0 + t * 64 + arow) * HID + k0 + acol,
               As + t * 2048 + wv * 512);
      gl_lds16(wptr + (size_t)(t * 64 + arow) * HID + k0 + acol,
               Bs + t * 2048 + wv * 512);
    }
    __syncthreads();
#pragma unroll
    for (int kh = 0; kh < 2; kh++) {
      bf16x8 af[2], bfr[2];
#pragma unroll
      for (int mt = 0; mt < 2; mt++)
        af[mt] = *(const bf16x8*)&As[(wm + mt * 32 + l32) * 32 + kh * 16 + hi * 8];
#pragma unroll
      for (int nt = 0; nt < 2; nt++)
        bfr[nt] = *(const bf16x8*)&Bs[(wn + nt * 32 + l32) * 32 + kh * 16 + hi * 8];
#pragma unroll
      for (int mt = 0; mt < 2; mt++)
#pragma unroll
        for (int nt = 0; nt < 2; nt++)
          acc[mt][nt] = __builtin_amdgcn_mfma_f32_32x32x16_bf16(af[mt], bfr[nt], acc[mt][nt], 0, 0, 0);
    }
  }

  float bv2[2];
#pragma unroll
  for (int nt = 0; nt < 2; nt++) bv2[nt] = bo[n0 + wn + nt * 32 + l32];
#pragma unroll
  for (int mt = 0; mt < 2; mt++) {
#pragma unroll
    for (int nt = 0; nt < 2; nt++) {
      int col = n0 + wn + nt * 32 + l32;
#pragma unroll
      for (int r = 0; r < 16; r++) {
        int mrow = m0 + wm + mt * 32 + (r & 3) + 8 * (r >> 2) + 4 * hi;
        size_t idx = (size_t)mrow * HID + col;
        out[idx] = acc[mt][nt][r] + bv2[nt] + x[idx];
      }
    }
  }
}

extern "C" void kernel_launch(void* const* d_in, const int* in_sizes, int n_in,
                              void* d_out, int out_size, void* d_ws, size_t ws_size,
                              hipStream_t stream) {
  const float* x    = (const float*)d_in[0];
  const float* Wq   = (const float*)d_in[1];
  const float* bq   = (const float*)d_in[2];
  const float* Wk   = (const float*)d_in[3];
  const float* bk   = (const float*)d_in[4];
  const float* Wv   = (const float*)d_in[5];
  const float* bv   = (const float*)d_in[6];
  const float* Wo   = (const float*)d_in[7];
  const float* bo   = (const float*)d_in[8];
  const float* ln_g = (const float*)d_in[9];
  const float* ln_b = (const float*)d_in[10];
  float* out = (float*)d_out;

  const size_t MB = 1024 * 1024;
  ushort* ws_w = (ushort*)d_ws;                         // weights bf16, 8 MB
  ushort* xn   = (ushort*)((char*)d_ws + 8 * MB);
  ushort* Qw   = (ushort*)((char*)d_ws + 16 * MB);
  ushort* Kw   = (ushort*)((char*)d_ws + 24 * MB);
  ushort* Vw   = (ushort*)((char*)d_ws + 32 * MB);      // transposed [bh][d][s]
  ushort* Cw   = (ushort*)((char*)d_ws + 40 * MB);

  k_cvt<<<dim3(1024, 4), 256, 0, stream>>>(Wq, Wk, Wv, Wo, ws_w);
  k_ln<<<dim3(MROWS), 256, 0, stream>>>(x, ln_g, ln_b, xn);
  k_qkv<<<dim3(32, 24), 256, 0, stream>>>(xn, ws_w, bq, bk, bv, Qw, Kw, Vw);
  k_attn<<<dim3(BATCH * NHEADS, SEQ / 128), 256, 0, stream>>>(Qw, Kw, Vw, Cw);
  k_oproj<<<dim3(32, 8), 256, 0, stream>>>(Cw, ws_w, bo, x, out);
}

// Round 11
// 200.175 us; speedup vs baseline: 1.0777x; 1.0777x over previous
//
#include <hip/hip_runtime.h>
#include <hip/hip_bf16.h>
#include <stdint.h>

// Problem constants
#define HID 1024
#define SEQ 2048
#define BATCH 2
#define NHEADS 16
#define HEADDIM 64
#define MROWS (BATCH*SEQ)   // 4096

#define GAS __attribute__((address_space(1)))
#define LAS __attribute__((address_space(3)))

typedef __attribute__((ext_vector_type(8))) __bf16 bf16x8;
typedef __attribute__((ext_vector_type(4))) float f32x4;
typedef __attribute__((ext_vector_type(16))) float f32x16;

__device__ __forceinline__ ushort f2bf(float f) {
  union { float f; uint32_t u; } v; v.f = f;
  return (ushort)((v.u + 0x7FFFu + ((v.u >> 16) & 1u)) >> 16);
}

__device__ __forceinline__ void gl_lds16(const void* g, void* l) {
  __builtin_amdgcn_global_load_lds((const GAS void*)g, (LAS void*)l, 16, 0, 0);
}

// pack 2 f32 -> 2 bf16 in one u32 (lo = a, hi = b), RNE
__device__ __forceinline__ uint32_t cvtpk(float a, float b) {
  uint32_t r;
  asm("v_cvt_pk_bf16_f32 %0, %1, %2" : "=v"(r) : "v"(a), "v"(b));
  return r;
}

// swap: a_hi <-> b_lo  =>  a' = [a_lo, b_lo], b' = [a_hi, b_hi]
__device__ __forceinline__ void pl32swap(uint32_t& a, uint32_t& b) {
  asm("v_permlane32_swap_b32 %0, %1" : "+v"(a), "+v"(b));
}

// ---------------- weight fp32 -> bf16 convert ----------------
__global__ __launch_bounds__(256) void k_cvt(const float* __restrict__ Wq,
                                             const float* __restrict__ Wk,
                                             const float* __restrict__ Wv,
                                             const float* __restrict__ Wo,
                                             ushort* __restrict__ dst) {
  int mat = blockIdx.y;
  const float* src = (mat == 0) ? Wq : (mat == 1) ? Wk : (mat == 2) ? Wv : Wo;
  int off = (blockIdx.x * 256 + threadIdx.x) * 4;
  float4 v = *(const float4*)(src + off);
  ushort4 o;
  o.x = f2bf(v.x); o.y = f2bf(v.y); o.z = f2bf(v.z); o.w = f2bf(v.w);
  *(ushort4*)(dst + (size_t)mat * (HID * HID) + off) = o;
}

// ---------------- LayerNorm fp32 -> bf16 ----------------
__global__ __launch_bounds__(256) void k_ln(const float* __restrict__ x,
                                            const float* __restrict__ g,
                                            const float* __restrict__ b,
                                            ushort* __restrict__ xn) {
  int row = blockIdx.x;
  int t = threadIdx.x;
  const float* xr = x + (size_t)row * HID;
  float4 v = *(const float4*)(xr + t * 4);
  float s = v.x + v.y + v.z + v.w;
  float s2 = v.x * v.x + v.y * v.y + v.z * v.z + v.w * v.w;
  for (int m = 1; m < 64; m <<= 1) { s += __shfl_xor(s, m); s2 += __shfl_xor(s2, m); }
  __shared__ float ws[4], ws2[4];
  int wid = t >> 6;
  if ((t & 63) == 0) { ws[wid] = s; ws2[wid] = s2; }
  __syncthreads();
  s = ws[0] + ws[1] + ws[2] + ws[3];
  s2 = ws2[0] + ws2[1] + ws2[2] + ws2[3];
  float mu = s * (1.0f / HID);
  float var = s2 * (1.0f / HID) - mu * mu;
  float rstd = rsqrtf(var + 1e-5f);
  float4 gg = *(const float4*)(g + t * 4);
  float4 bb = *(const float4*)(b + t * 4);
  ushort4 o;
  o.x = f2bf((v.x - mu) * rstd * gg.x + bb.x);
  o.y = f2bf((v.y - mu) * rstd * gg.y + bb.y);
  o.z = f2bf((v.z - mu) * rstd * gg.z + bb.z);
  o.w = f2bf((v.w - mu) * rstd * gg.w + bb.w);
  *(ushort4*)(xn + (size_t)row * HID + t * 4) = o;
}

// ---------------- fused QKV GEMM (round-5 16x16 version: reverted) ----------------
// 32x32 variant REGRESSED (57us, 9.4M bank-conflict cycles): unswizzled [row][32]
// tile at 64B stride -> 16-way conflicts (even lanes all on banks 0-3). The old
// 16x16 quad*16B pattern is conflict-minimal (8 bank-bases). Keep it.
__global__ __launch_bounds__(256) void k_qkv(const ushort* __restrict__ xn,
                                             const ushort* __restrict__ wmat,
                                             const float* __restrict__ bq,
                                             const float* __restrict__ bk,
                                             const float* __restrict__ bv,
                                             ushort* __restrict__ qo,
                                             ushort* __restrict__ ko,
                                             ushort* __restrict__ vo) {
  __shared__ ushort As[128 * 32];
  __shared__ ushort Bs[128 * 32];
  int tid = threadIdx.x;
  int lane = tid & 63;
  int wv = tid >> 6;
  int quad = lane >> 4;
  int l16 = lane & 15;
  int m0 = blockIdx.x * 128;
  int ng = blockIdx.y * 128;
  int mat = ng >> 10;            // 0,1,2
  int nloc = ng & 1023;
  const ushort* wptr = wmat + (size_t)mat * (HID * HID) + (size_t)nloc * HID;
  const float* bias = (mat == 0) ? bq : (mat == 1) ? bk : bv;
  ushort* outp = (mat == 0) ? qo : (mat == 1) ? ko : vo;
  const float scl = (mat == 0) ? 0.18033688011112042f : 1.0f;

  int arow = tid >> 2;
  int acol = (tid & 3) * 8;
  int wm = (wv >> 1) * 64, wn = (wv & 1) * 64;

  f32x4 acc[4][4] = {};
  for (int k0 = 0; k0 < HID; k0 += 32) {
    __syncthreads();
    for (int t = 0; t < 2; t++) {
      gl_lds16(xn + (size_t)(m0 + t * 64 + arow) * HID + k0 + acol,
               As + t * 2048 + wv * 512);
      gl_lds16(wptr + (size_t)(t * 64 + arow) * HID + k0 + acol,
               Bs + t * 2048 + wv * 512);
    }
    __syncthreads();
    bf16x8 af[4], bfr[4];
    for (int i = 0; i < 4; i++)
      af[i] = *(const bf16x8*)&As[(wm + i * 16 + l16) * 32 + quad * 8];
    for (int n = 0; n < 4; n++)
      bfr[n] = *(const bf16x8*)&Bs[(wn + n * 16 + l16) * 32 + quad * 8];
    for (int i = 0; i < 4; i++)
      for (int n = 0; n < 4; n++)
        acc[i][n] = __builtin_amdgcn_mfma_f32_16x16x32_bf16(af[i], bfr[n], acc[i][n], 0, 0, 0);
  }
  float bv4[4];
  for (int n = 0; n < 4; n++) bv4[n] = bias[nloc + wn + n * 16 + l16];
  for (int i = 0; i < 4; i++) {
    int mrow = m0 + wm + i * 16 + quad * 4;
    for (int n = 0; n < 4; n++) {
      int col = nloc + wn + n * 16 + l16;
      int h = col >> 6, d = col & 63;
      for (int r = 0; r < 4; r++) {
        int m = mrow + r;
        int bidx = m >> 11, sidx = m & 2047;
        size_t dst;
        if (mat == 2)  // V transposed: [bh][d][s]
          dst = (((size_t)(bidx * NHEADS + h) * HEADDIM) + d) * SEQ + sidx;
        else
          dst = (((size_t)(bidx * NHEADS + h) * SEQ) + sidx) * HEADDIM + d;
        outp[dst] = f2bf((acc[i][n][r] + bv4[n]) * scl);
      }
    }
  }
}

// ---------------- flash attention v6 (proven 52.0us x3) ----------------
#define E2(x) __builtin_amdgcn_exp2f(x)

#define SOFTMAX_PF(S0, S1)                                                     \
    union { uint32_t u[4]; bf16x8 v; } pf0, pf1, pf2, pf3;                     \
    {                                                                          \
      uint32_t c0 = cvtpk(E2(S0[0]),  E2(S0[1]));                              \
      uint32_t c1 = cvtpk(E2(S0[2]),  E2(S0[3]));                              \
      uint32_t c2 = cvtpk(E2(S0[4]),  E2(S0[5]));                              \
      uint32_t c3 = cvtpk(E2(S0[6]),  E2(S0[7]));                              \
      uint32_t c4 = cvtpk(E2(S0[8]),  E2(S0[9]));                              \
      uint32_t c5 = cvtpk(E2(S0[10]), E2(S0[11]));                             \
      uint32_t c6 = cvtpk(E2(S0[12]), E2(S0[13]));                             \
      uint32_t c7 = cvtpk(E2(S0[14]), E2(S0[15]));                             \
      pl32swap(c0, c2); pl32swap(c1, c3); pl32swap(c4, c6); pl32swap(c5, c7);  \
      pf0.u[0] = c0; pf0.u[1] = c1; pf0.u[2] = c2; pf0.u[3] = c3;              \
      pf1.u[0] = c4; pf1.u[1] = c5; pf1.u[2] = c6; pf1.u[3] = c7;              \
    }                                                                          \
    {                                                                          \
      uint32_t c0 = cvtpk(E2(S1[0]),  E2(S1[1]));                              \
      uint32_t c1 = cvtpk(E2(S1[2]),  E2(S1[3]));                              \
      uint32_t c2 = cvtpk(E2(S1[4]),  E2(S1[5]));                              \
      uint32_t c3 = cvtpk(E2(S1[6]),  E2(S1[7]));                              \
      uint32_t c4 = cvtpk(E2(S1[8]),  E2(S1[9]));                              \
      uint32_t c5 = cvtpk(E2(S1[10]), E2(S1[11]));                             \
      uint32_t c6 = cvtpk(E2(S1[12]), E2(S1[13]));                             \
      uint32_t c7 = cvtpk(E2(S1[14]), E2(S1[15]));                             \
      pl32swap(c0, c2); pl32swap(c1, c3); pl32swap(c4, c6); pl32swap(c5, c7);  \
      pf2.u[0] = c0; pf2.u[1] = c1; pf2.u[2] = c2; pf2.u[3] = c3;              \
      pf3.u[0] = c4; pf3.u[1] = c5; pf3.u[2] = c6; pf3.u[3] = c7;              \
    }

#define ATTN_BODY(T, SC0, SC1, SP0, SP1, DO_DMA, WAITN)                        \
  do {                                                                         \
    if (DO_DMA) {                                                              \
      size_t ko = (size_t)((T) + 2) * 64 * HEADDIM;                            \
      size_t vo = (size_t)((T) + 2) * 64;                                      \
      gl_lds16(kSrcA + ko, &Ksm[kd][ldsA]);                                    \
      gl_lds16(kSrcB + ko, &Ksm[kd][ldsB]);                                    \
      gl_lds16(vSrcA + vo, &Vsm[vd][ldsA]);                                    \
      gl_lds16(vSrcB + vo, &Vsm[vd][ldsB]);                                    \
    }                                                                          \
    SC0 = (f32x16){}; SC1 = (f32x16){};                                        \
    __builtin_amdgcn_s_setprio(1);                                             \
    _Pragma("unroll")                                                          \
    for (int f = 0; f < 4; f++) {                                              \
      int g = 2 * f + hi;                                                      \
      bf16x8 k0 = *(const bf16x8*)&Ksm[kr][l32 * 64 + ((g ^ rsw) * 8)];        \
      bf16x8 k1 = *(const bf16x8*)&Ksm[kr][(32 + l32) * 64 + ((g ^ rsw) * 8)]; \
      SC0 = __builtin_amdgcn_mfma_f32_32x32x16_bf16(k0, qf[f], SC0, 0, 0, 0);  \
      SC1 = __builtin_amdgcn_mfma_f32_32x32x16_bf16(k1, qf[f], SC1, 0, 0, 0);  \
    }                                                                          \
    __builtin_amdgcn_s_setprio(0);                                             \
    bf16x8 vf[8];                                                              \
    _Pragma("unroll")                                                          \
    for (int kf = 0; kf < 4; kf++) {                                           \
      int g = 2 * kf + hi;                                                     \
      vf[2 * kf]     = *(const bf16x8*)&Vsm[vr][l32 * 64 + ((g ^ rsw) * 8)];   \
      vf[2 * kf + 1] = *(const bf16x8*)&Vsm[vr][(32 + l32) * 64 + ((g ^ rsw) * 8)]; \
    }                                                                          \
    SOFTMAX_PF(SP0, SP1)                                                       \
    __builtin_amdgcn_s_setprio(1);                                             \
    _Pragma("unroll")                                                          \
    for (int kf = 0; kf < 4; kf++) {                                           \
      bf16x8 pv = (kf == 0) ? pf0.v : (kf == 1) ? pf1.v : (kf == 2) ? pf2.v : pf3.v; \
      Oa0 = __builtin_amdgcn_mfma_f32_32x32x16_bf16(pv, vf[2 * kf], Oa0, 0, 0, 0);   \
      Oa1 = __builtin_amdgcn_mfma_f32_32x32x16_bf16(pv, vf[2 * kf + 1], Oa1, 0, 0, 0); \
      Os  = __builtin_amdgcn_mfma_f32_32x32x16_bf16(pv, ones, Os, 0, 0, 0);    \
    }                                                                          \
    __builtin_amdgcn_s_setprio(0);                                             \
    asm volatile("s_waitcnt vmcnt(" #WAITN ")" ::: "memory");                  \
    __builtin_amdgcn_s_barrier();                                              \
    __builtin_amdgcn_sched_barrier(0);                                         \
    kr = (kr == 2) ? 0 : kr + 1;                                               \
    kd = (kd == 2) ? 0 : kd + 1;                                               \
    vr = (vr + 1) & 3;                                                         \
    vd = (vd + 1) & 3;                                                         \
  } while (0)

__global__ __launch_bounds__(256, 2) void k_attn(const ushort* __restrict__ Q,
                                                 const ushort* __restrict__ K,
                                                 const ushort* __restrict__ Vt,
                                                 ushort* __restrict__ ctx) {
  __shared__ ushort Ksm[3][64 * 64];   // 24 KB
  __shared__ ushort Vsm[4][64 * 64];   // 32 KB
  int tid = threadIdx.x, lane = tid & 63, wv = tid >> 6;
  int l32 = lane & 31, hi = lane >> 5;
  int bh = blockIdx.x;                 // XCD-grouped: id%8 == bh%8 (v5)
  int q0 = blockIdx.y * 128;
  const ushort* Qb = Q + ((size_t)bh * SEQ + q0 + wv * 32 + l32) * HEADDIM;
  const ushort* Kb = K + (size_t)bh * SEQ * HEADDIM;
  const ushort* Vb = Vt + (size_t)bh * HEADDIM * SEQ;   // [d][s]

  // Q as B-frag: col=l32 (q-row), k(d) = f*16 + hi*8 + j. Pre-scaled by 0.125*log2e.
  bf16x8 qf[4];
#pragma unroll
  for (int f = 0; f < 4; f++)
    qf[f] = *(const bf16x8*)(Qb + f * 16 + hi * 8);

  bf16x8 ones;
#pragma unroll
  for (int j = 0; j < 8; j++) ones[j] = (__bf16)1.0f;

  int gsl = lane & 7;
  int rowA = wv * 8 + (lane >> 3);        // rows 0..31
  int rowB = 32 + wv * 8 + (lane >> 3);   // rows 32..63
  const ushort* kSrcA = Kb + rowA * HEADDIM + ((gsl ^ (rowA & 7)) * 8);
  const ushort* kSrcB = Kb + rowB * HEADDIM + ((gsl ^ (rowB & 7)) * 8);
  const ushort* vSrcA = Vb + (size_t)rowA * SEQ + ((gsl ^ (rowA & 7)) * 8);
  const ushort* vSrcB = Vb + (size_t)rowB * SEQ + ((gsl ^ (rowB & 7)) * 8);
  int ldsA = wv * 512;          // ushort idx (1 KB per wave-issue)
  int ldsB = 2048 + wv * 512;

  f32x16 Oa0 = {}, Oa1 = {}, Os = {};
  f32x16 sA0, sA1, sB0, sB1;
  int rsw = (l32 & 7);   // read-side swizzle key

  // prologue: stage tile 0 -> K[0]/V[0], tile 1 -> K[1]/V[1].
  gl_lds16(kSrcA, &Ksm[0][ldsA]);
  gl_lds16(kSrcB, &Ksm[0][ldsB]);
  gl_lds16(vSrcA, &Vsm[0][ldsA]);
  gl_lds16(vSrcB, &Vsm[0][ldsB]);
  gl_lds16(kSrcA + 64 * HEADDIM, &Ksm[1][ldsA]);
  gl_lds16(kSrcB + 64 * HEADDIM, &Ksm[1][ldsB]);
  gl_lds16(vSrcA + 64, &Vsm[1][ldsA]);
  gl_lds16(vSrcB + 64, &Vsm[1][ldsB]);
  asm volatile("s_waitcnt vmcnt(4)" ::: "memory");   // tile0 landed
  __builtin_amdgcn_s_barrier();
  __builtin_amdgcn_sched_barrier(0);

  // t = 0 (peeled): DMA tile 2 -> K[2]/V[2], QK(0) -> sA. No softmax/PV yet.
  {
    gl_lds16(kSrcA + 2 * 64 * HEADDIM, &Ksm[2][ldsA]);
    gl_lds16(kSrcB + 2 * 64 * HEADDIM, &Ksm[2][ldsB]);
    gl_lds16(vSrcA + 2 * 64, &Vsm[2][ldsA]);
    gl_lds16(vSrcB + 2 * 64, &Vsm[2][ldsB]);
    sA0 = (f32x16){}; sA1 = (f32x16){};
    __builtin_amdgcn_s_setprio(1);
#pragma unroll
    for (int f = 0; f < 4; f++) {
      int g = 2 * f + hi;
      bf16x8 k0 = *(const bf16x8*)&Ksm[0][l32 * 64 + ((g ^ rsw) * 8)];
      bf16x8 k1 = *(const bf16x8*)&Ksm[0][(32 + l32) * 64 + ((g ^ rsw) * 8)];
      sA0 = __builtin_amdgcn_mfma_f32_32x32x16_bf16(k0, qf[f], sA0, 0, 0, 0);
      sA1 = __builtin_amdgcn_mfma_f32_32x32x16_bf16(k1, qf[f], sA1, 0, 0, 0);
    }
    __builtin_amdgcn_s_setprio(0);
    asm volatile("s_waitcnt vmcnt(4)" ::: "memory");   // tile1 landed; tile2 in flight
    __builtin_amdgcn_s_barrier();
    __builtin_amdgcn_sched_barrier(0);
  }

  // steady state. At entry of body t: kr=t%3, kd=(t+2)%3, vr=(t-1)%4, vd=(t+2)%4.
  int kr = 1, kd = 0, vr = 0, vd = 3;
  for (int t = 1; t < 29; t += 2) {
    ATTN_BODY(t,     sB0, sB1, sA0, sA1, true, 4);
    ATTN_BODY(t + 1, sA0, sA1, sB0, sB1, true, 4);
  }
  ATTN_BODY(29, sB0, sB1, sA0, sA1, true, 4);
  ATTN_BODY(30, sA0, sA1, sB0, sB1, false, 0);   // last landing: tile31 must arrive

  // t = 31 tail: QK(31) -> sB from K[31%3=1], softmax+PV(30) from V[30%4=2].
  {
    sB0 = (f32x16){}; sB1 = (f32x16){};
    __builtin_amdgcn_s_setprio(1);
#pragma unroll
    for (int f = 0; f < 4; f++) {
      int g = 2 * f + hi;
      bf16x8 k0 = *(const bf16x8*)&Ksm[kr][l32 * 64 + ((g ^ rsw) * 8)];
      bf16x8 k1 = *(const bf16x8*)&Ksm[kr][(32 + l32) * 64 + ((g ^ rsw) * 8)];
      sB0 = __builtin_amdgcn_mfma_f32_32x32x16_bf16(k0, qf[f], sB0, 0, 0, 0);
      sB1 = __builtin_amdgcn_mfma_f32_32x32x16_bf16(k1, qf[f], sB1, 0, 0, 0);
    }
    __builtin_amdgcn_s_setprio(0);
    bf16x8 vf[8];
#pragma unroll
    for (int kf = 0; kf < 4; kf++) {
      int g = 2 * kf + hi;
      vf[2 * kf]     = *(const bf16x8*)&Vsm[vr][l32 * 64 + ((g ^ rsw) * 8)];
      vf[2 * kf + 1] = *(const bf16x8*)&Vsm[vr][(32 + l32) * 64 + ((g ^ rsw) * 8)];
    }
    SOFTMAX_PF(sA0, sA1)
    __builtin_amdgcn_s_setprio(1);
#pragma unroll
    for (int kf = 0; kf < 4; kf++) {
      bf16x8 pv = (kf == 0) ? pf0.v : (kf == 1) ? pf1.v : (kf == 2) ? pf2.v : pf3.v;
      Oa0 = __builtin_amdgcn_mfma_f32_32x32x16_bf16(pv, vf[2 * kf], Oa0, 0, 0, 0);
      Oa1 = __builtin_amdgcn_mfma_f32_32x32x16_bf16(pv, vf[2 * kf + 1], Oa1, 0, 0, 0);
      Os  = __builtin_amdgcn_mfma_f32_32x32x16_bf16(pv, ones, Os, 0, 0, 0);
    }
    __builtin_amdgcn_s_setprio(0);
    vr = (vr + 1) & 3;   // -> 31%4 = 3 for the epilogue PV(31)
  }

  // epilogue: softmax+PV of tile 31 (scores in sB, V(31) in Vsm[3])
  {
    bf16x8 vf[8];
#pragma unroll
    for (int kf = 0; kf < 4; kf++) {
      int g = 2 * kf + hi;
      vf[2 * kf]     = *(const bf16x8*)&Vsm[vr][l32 * 64 + ((g ^ rsw) * 8)];
      vf[2 * kf + 1] = *(const bf16x8*)&Vsm[vr][(32 + l32) * 64 + ((g ^ rsw) * 8)];
    }
    SOFTMAX_PF(sB0, sB1)
    __builtin_amdgcn_s_setprio(1);
#pragma unroll
    for (int kf = 0; kf < 4; kf++) {
      bf16x8 pv = (kf == 0) ? pf0.v : (kf == 1) ? pf1.v : (kf == 2) ? pf2.v : pf3.v;
      Oa0 = __builtin_amdgcn_mfma_f32_32x32x16_bf16(pv, vf[2 * kf], Oa0, 0, 0, 0);
      Oa1 = __builtin_amdgcn_mfma_f32_32x32x16_bf16(pv, vf[2 * kf + 1], Oa1, 0, 0, 0);
      Os  = __builtin_amdgcn_mfma_f32_32x32x16_bf16(pv, ones, Os, 0, 0, 0);
    }
    __builtin_amdgcn_s_setprio(0);
  }

  // epilogue: ctx[b*2048+s][h*64+d] bf16. q in regs: (r&3)+8*(r>>2)+4*hi.
  int bidx = bh >> 4, h = bh & 15;
#pragma unroll
  for (int r = 0; r < 16; r++) {
    float inv = 1.0f / Os[r];
    int qloc = (r & 3) + 8 * (r >> 2) + 4 * hi;
    int sidx = q0 + wv * 32 + qloc;
    size_t base = ((size_t)(bidx * SEQ) + sidx) * HID + h * HEADDIM;
    ctx[base + l32]      = f2bf(Oa0[r] * inv);
    ctx[base + 32 + l32] = f2bf(Oa1[r] * inv);
  }
}

// ---------------- output projection (v4: 64x64 tiles for occupancy) ----------------
// Old grid (32,8) = 256 blocks = 1 block/CU = 2 waves/SIMD -> same occupancy
// disease attn had. New: 64x64 tiles, grid (64,16) = 1024 blocks = 4/CU =
// 4 waves/SIMD. LDS 8KB. Fragment math identical to the verified 16x16 qkv
// pattern, per wave 32x32 output (acc[2][2]).
__global__ __launch_bounds__(256) void k_oproj(const ushort* __restrict__ ctx,
                                               const ushort* __restrict__ wmat,
                                               const float* __restrict__ bo,
                                               const float* __restrict__ x,
                                               float* __restrict__ out) {
  __shared__ ushort As[64 * 32];
  __shared__ ushort Bs[64 * 32];
  int tid = threadIdx.x;
  int lane = tid & 63;
  int wv = tid >> 6;
  int quad = lane >> 4;
  int l16 = lane & 15;
  int m0 = blockIdx.x * 64;
  int n0 = blockIdx.y * 64;
  const ushort* wptr = wmat + (size_t)3 * (HID * HID) + (size_t)n0 * HID;  // Wo
  int arow = tid >> 2;           // 0..63
  int acol = (tid & 3) * 8;
  int wm = (wv >> 1) * 32, wn = (wv & 1) * 32;

  f32x4 acc[2][2] = {};
  for (int k0 = 0; k0 < HID; k0 += 32) {
    __syncthreads();
    gl_lds16(ctx + (size_t)(m0 + arow) * HID + k0 + acol, As + wv * 512);
    gl_lds16(wptr + (size_t)arow * HID + k0 + acol, Bs + wv * 512);
    __syncthreads();
    bf16x8 af[2], bfr[2];
    for (int i = 0; i < 2; i++)
      af[i] = *(const bf16x8*)&As[(wm + i * 16 + l16) * 32 + quad * 8];
    for (int n = 0; n < 2; n++)
      bfr[n] = *(const bf16x8*)&Bs[(wn + n * 16 + l16) * 32 + quad * 8];
    for (int i = 0; i < 2; i++)
      for (int n = 0; n < 2; n++)
        acc[i][n] = __builtin_amdgcn_mfma_f32_16x16x32_bf16(af[i], bfr[n], acc[i][n], 0, 0, 0);
  }
  float bv2[2];
  for (int n = 0; n < 2; n++) bv2[n] = bo[n0 + wn + n * 16 + l16];
  for (int i = 0; i < 2; i++) {
    int mrow = m0 + wm + i * 16 + quad * 4;
    for (int n = 0; n < 2; n++) {
      int col = n0 + wn + n * 16 + l16;
      for (int r = 0; r < 4; r++) {
        size_t idx = (size_t)(mrow + r) * HID + col;
        out[idx] = acc[i][n][r] + bv2[n] + x[idx];
      }
    }
  }
}

extern "C" void kernel_launch(void* const* d_in, const int* in_sizes, int n_in,
                              void* d_out, int out_size, void* d_ws, size_t ws_size,
                              hipStream_t stream) {
  const float* x    = (const float*)d_in[0];
  const float* Wq   = (const float*)d_in[1];
  const float* bq   = (const float*)d_in[2];
  const float* Wk   = (const float*)d_in[3];
  const float* bk   = (const float*)d_in[4];
  const float* Wv   = (const float*)d_in[5];
  const float* bv   = (const float*)d_in[6];
  const float* Wo   = (const float*)d_in[7];
  const float* bo   = (const float*)d_in[8];
  const float* ln_g = (const float*)d_in[9];
  const float* ln_b = (const float*)d_in[10];
  float* out = (float*)d_out;

  const size_t MB = 1024 * 1024;
  ushort* ws_w = (ushort*)d_ws;                         // weights bf16, 8 MB
  ushort* xn   = (ushort*)((char*)d_ws + 8 * MB);
  ushort* Qw   = (ushort*)((char*)d_ws + 16 * MB);
  ushort* Kw   = (ushort*)((char*)d_ws + 24 * MB);
  ushort* Vw   = (ushort*)((char*)d_ws + 32 * MB);      // transposed [bh][d][s]
  ushort* Cw   = (ushort*)((char*)d_ws + 40 * MB);

  k_cvt<<<dim3(1024, 4), 256, 0, stream>>>(Wq, Wk, Wv, Wo, ws_w);
  k_ln<<<dim3(MROWS), 256, 0, stream>>>(x, ln_g, ln_b, xn);
  k_qkv<<<dim3(32, 24), 256, 0, stream>>>(xn, ws_w, bq, bk, bv, Qw, Kw, Vw);
  k_attn<<<dim3(BATCH * NHEADS, SEQ / 128), 256, 0, stream>>>(Qw, Kw, Vw, Cw);
  k_oproj<<<dim3(64, 16), 256, 0, stream>>>(Cw, ws_w, bo, x, out);
}